// Round 1
// baseline (643.933 us; speedup 1.0000x reference)
//
#include <hip/hip_runtime.h>

#define N_NODES 50000
#define N_EDGES 800000
#define N_GRAPHS 512
#define F_IN 128
#define HDIM 64

// ---------------- degree / norm ----------------
__global__ __launch_bounds__(256) void deg_init(float* deg) {
    int i = blockIdx.x * 256 + threadIdx.x;
    if (i < N_NODES) deg[i] = 1.0f;            // self-loop counts 1
}

__global__ __launch_bounds__(256) void deg_count(const int* dst, float* deg) {
    int e = blockIdx.x * 256 + threadIdx.x;
    if (e < N_EDGES) atomicAdd(&deg[dst[e]], 1.0f);
}

__global__ __launch_bounds__(256) void deg_rsqrt(float* deg) {
    int i = blockIdx.x * 256 + threadIdx.x;
    if (i < N_NODES) deg[i] = rsqrtf(deg[i]);  // deg >= 1 always
}

// ---------------- layer 1: xw = x @ W1 ; agg1 seeded with self-loop ----------------
// one wave (64 lanes) per node; W1 (128x64) staged in LDS; x row staged in LDS.
__global__ __launch_bounds__(256) void xw1_kernel(const float* __restrict__ x,
                                                  const float* __restrict__ W1,
                                                  const float* __restrict__ dinv,
                                                  float* __restrict__ xw,
                                                  float* __restrict__ agg) {
    __shared__ float Ws[F_IN * HDIM];    // 32 KiB
    __shared__ float xs[4][F_IN];        // 2 KiB
    int t = threadIdx.x;
    for (int i = t; i < F_IN * HDIM; i += 256) Ws[i] = W1[i];

    int w = t >> 6, lane = t & 63;
    int node = blockIdx.x * 4 + w;
    if (node < N_NODES) {
        const float* xr = x + node * F_IN;
        xs[w][lane]      = xr[lane];
        xs[w][lane + 64] = xr[lane + 64];
    }
    __syncthreads();
    if (node < N_NODES) {
        float acc = 0.f;
        #pragma unroll 16
        for (int k = 0; k < F_IN; ++k) acc += xs[w][k] * Ws[k * HDIM + lane];
        float di = dinv[node];
        xw[node * HDIM + lane]  = acc;
        agg[node * HDIM + lane] = acc * di * di;   // self-loop message
    }
}

// ---------------- edge scatter: agg[dst] += xw[src] * dinv[src]*dinv[dst] ----------------
// thread = (edge, feature). 64 consecutive threads share one edge -> coalesced 256B
// gather from xw[src] and coalesced 256B atomic burst to agg[dst].
__global__ __launch_bounds__(256) void gcn_scatter(const int* __restrict__ src,
                                                   const int* __restrict__ dst,
                                                   const float* __restrict__ dinv,
                                                   const float* __restrict__ xw,
                                                   float* __restrict__ agg) {
    int idx = blockIdx.x * 256 + threadIdx.x;
    int e = idx >> 6, lane = idx & 63;
    if (e < N_EDGES) {
        int s = src[e], d = dst[e];
        float nrm = dinv[s] * dinv[d];
        atomicAdd(&agg[d * HDIM + lane], xw[s * HDIM + lane] * nrm);
    }
}

// ---------------- layer 2 input: h1 = relu(agg1+b1); xw2 = h1 @ W2; seed agg2 ----------------
__global__ __launch_bounds__(256) void conv2_kernel(const float* __restrict__ agg1,
                                                    const float* __restrict__ b1,
                                                    const float* __restrict__ W2,
                                                    const float* __restrict__ dinv,
                                                    float* __restrict__ xw2,
                                                    float* __restrict__ agg2) {
    __shared__ float Ws[HDIM * HDIM];   // 16 KiB
    __shared__ float h1s[4][HDIM];
    int t = threadIdx.x;
    for (int i = t; i < HDIM * HDIM; i += 256) Ws[i] = W2[i];

    int w = t >> 6, lane = t & 63;
    int node = blockIdx.x * 4 + w;
    float h1 = 0.f;
    if (node < N_NODES) h1 = fmaxf(agg1[node * HDIM + lane] + b1[lane], 0.f);
    h1s[w][lane] = h1;
    __syncthreads();
    if (node < N_NODES) {
        float acc = 0.f;
        #pragma unroll 16
        for (int k = 0; k < HDIM; ++k) acc += h1s[w][k] * Ws[k * HDIM + lane];
        float di = dinv[node];
        xw2[node * HDIM + lane]  = acc;
        agg2[node * HDIM + lane] = acc * di * di;
    }
}

// ---------------- mean-pool (relu fused) ----------------
__global__ __launch_bounds__(256) void pool_kernel(const float* __restrict__ agg2,
                                                   const float* __restrict__ b2,
                                                   const int* __restrict__ batch,
                                                   float* __restrict__ pool,
                                                   float* __restrict__ cnt) {
    int idx = blockIdx.x * 256 + threadIdx.x;
    int node = idx >> 6, lane = idx & 63;
    if (node < N_NODES) {
        int g = batch[node];
        float v = fmaxf(agg2[node * HDIM + lane] + b2[lane], 0.f);
        atomicAdd(&pool[g * HDIM + lane], v);
        if (lane == 0) atomicAdd(&cnt[g], 1.0f);
    }
}

// ---------------- final MLP: out = relu(pooled@Wf1+bf1)@Wf2 + bf2 ----------------
__global__ __launch_bounds__(128) void mlp_kernel(const float* __restrict__ pool,
                                                  const float* __restrict__ cnt,
                                                  const float* __restrict__ Wf1,
                                                  const float* __restrict__ bf1,
                                                  const float* __restrict__ Wf2,
                                                  const float* __restrict__ bf2,
                                                  float* __restrict__ out) {
    int g = blockIdx.x;
    __shared__ float pooled[HDIM];
    __shared__ float wsum[2];
    int t = threadIdx.x;
    if (t < HDIM) {
        float c = fmaxf(cnt[g], 1.0f);
        pooled[t] = pool[g * HDIM + t] / c;
    }
    __syncthreads();
    float acc = bf1[t];
    #pragma unroll 8
    for (int k = 0; k < HDIM; ++k) acc += pooled[k] * Wf1[k * 128 + t];
    acc = fmaxf(acc, 0.f) * Wf2[t];
    #pragma unroll
    for (int off = 32; off > 0; off >>= 1) acc += __shfl_down(acc, off);
    if ((t & 63) == 0) wsum[t >> 6] = acc;
    __syncthreads();
    if (t == 0) out[g] = wsum[0] + wsum[1] + bf2[0];
}

extern "C" void kernel_launch(void* const* d_in, const int* in_sizes, int n_in,
                              void* d_out, int out_size, void* d_ws, size_t ws_size,
                              hipStream_t stream) {
    const float* x    = (const float*)d_in[0];
    const int*   ei   = (const int*)d_in[1];
    const int*   src  = ei;                 // edge_index[0]
    const int*   dst  = ei + N_EDGES;       // edge_index[1]
    const int*   batch= (const int*)d_in[2];
    const float* W1   = (const float*)d_in[3];
    const float* b1   = (const float*)d_in[4];
    const float* W2   = (const float*)d_in[5];
    const float* b2   = (const float*)d_in[6];
    const float* Wf1  = (const float*)d_in[7];
    const float* bf1  = (const float*)d_in[8];
    const float* Wf2  = (const float*)d_in[9];
    const float* bf2  = (const float*)d_in[10];
    float* out = (float*)d_out;

    float* ws   = (float*)d_ws;
    float* buf0 = ws;                        // [N,64]  xw1, later agg2
    float* buf1 = buf0 + N_NODES * HDIM;     // [N,64]  agg1
    float* buf2 = buf1 + N_NODES * HDIM;     // [N,64]  xw2
    float* dinv = buf2 + N_NODES * HDIM;     // [N]     deg -> dinv
    float* pool = dinv + N_NODES;            // [G,64]
    float* cnt  = pool + N_GRAPHS * HDIM;    // [G]

    deg_init <<<(N_NODES + 255) / 256, 256, 0, stream>>>(dinv);
    deg_count<<<(N_EDGES + 255) / 256, 256, 0, stream>>>(dst, dinv);
    deg_rsqrt<<<(N_NODES + 255) / 256, 256, 0, stream>>>(dinv);

    xw1_kernel<<<(N_NODES + 3) / 4, 256, 0, stream>>>(x, W1, dinv, buf0, buf1);
    gcn_scatter<<<(N_EDGES * 64 + 255) / 256, 256, 0, stream>>>(src, dst, dinv, buf0, buf1);

    conv2_kernel<<<(N_NODES + 3) / 4, 256, 0, stream>>>(buf1, b1, W2, dinv, buf2, buf0);
    gcn_scatter<<<(N_EDGES * 64 + 255) / 256, 256, 0, stream>>>(src, dst, dinv, buf2, buf0);

    hipMemsetAsync(pool, 0, (N_GRAPHS * HDIM + N_GRAPHS) * sizeof(float), stream);
    pool_kernel<<<(N_NODES * 64 + 255) / 256, 256, 0, stream>>>(buf0, b2, batch, pool, cnt);

    mlp_kernel<<<N_GRAPHS, 128, 0, stream>>>(pool, cnt, Wf1, bf1, Wf2, bf2, out);
}

// Round 2
// 309.896 us; speedup vs baseline: 2.0779x; 2.0779x over previous
//
#include <hip/hip_runtime.h>

#define N_NODES 50000
#define N_EDGES 800000
#define N_GRAPHS 512
#define F_IN 128
#define HDIM 64
#define SCAN_CHUNK 1024
#define N_SCAN_BLOCKS ((N_NODES + SCAN_CHUNK - 1) / SCAN_CHUNK)  // 49

// ---------- CSR build ----------
__global__ __launch_bounds__(256) void count_k(const int* __restrict__ dst, int* __restrict__ cnt) {
    int e = blockIdx.x * 256 + threadIdx.x;
    if (e < N_EDGES) atomicAdd(&cnt[dst[e]], 1);
}

// block-level scan (1024 elems/block) + dinv = rsqrt(cnt+1)
__global__ __launch_bounds__(256) void scan1_k(const int* __restrict__ cnt, int* __restrict__ row,
                                               int* __restrict__ blksum, float* __restrict__ dinv) {
    __shared__ int s[256];
    int t = threadIdx.x, base = blockIdx.x * SCAN_CHUNK + t * 4;
    int c[4]; int sum = 0;
    #pragma unroll
    for (int j = 0; j < 4; ++j) { int i = base + j; c[j] = (i < N_NODES) ? cnt[i] : 0; sum += c[j]; }
    #pragma unroll
    for (int j = 0; j < 4; ++j) { int i = base + j; if (i < N_NODES) dinv[i] = rsqrtf((float)c[j] + 1.0f); }
    s[t] = sum; __syncthreads();
    for (int off = 1; off < 256; off <<= 1) {
        int v = (t >= off) ? s[t - off] : 0; __syncthreads();
        s[t] += v; __syncthreads();
    }
    int pre = s[t] - sum;   // exclusive prefix of thread sums
    #pragma unroll
    for (int j = 0; j < 4; ++j) { int i = base + j; if (i < N_NODES) row[i] = pre; pre += c[j]; }
    if (t == 255) blksum[blockIdx.x] = s[255];
}

__global__ __launch_bounds__(64) void scan2_k(int* blksum) {
    __shared__ int s[64];
    int t = threadIdx.x;
    int v = (t < N_SCAN_BLOCKS) ? blksum[t] : 0;
    s[t] = v; __syncthreads();
    for (int off = 1; off < 64; off <<= 1) {
        int u = (t >= off) ? s[t - off] : 0; __syncthreads();
        s[t] += u; __syncthreads();
    }
    if (t < N_SCAN_BLOCKS) blksum[t] = s[t] - v;  // exclusive
}

__global__ __launch_bounds__(256) void scan3_k(int* __restrict__ row, const int* __restrict__ blksum,
                                               int* __restrict__ cursor) {
    int i = blockIdx.x * 256 + threadIdx.x;
    if (i < N_NODES) { int r = row[i] + blksum[i / SCAN_CHUNK]; row[i] = r; cursor[i] = r; }
    if (i == 0) row[N_NODES] = N_EDGES;
}

__global__ __launch_bounds__(256) void fill_k(const int* __restrict__ src, const int* __restrict__ dst,
                                              int* __restrict__ cursor, int* __restrict__ csr_src) {
    int e = blockIdx.x * 256 + threadIdx.x;
    if (e < N_EDGES) { int p = atomicAdd(&cursor[dst[e]], 1); csr_src[p] = src[e]; }
}

// ---------- tiled GEMM: xw = x[50000,128] @ W1[128,64] ----------
// block = 256 threads, 64 nodes; thread: 4 nodes x float4 cols. LDS ~48.7KB -> 3 blocks/CU.
__global__ __launch_bounds__(256) void xw1_k(const float* __restrict__ x, const float* __restrict__ W1,
                                             float* __restrict__ xw) {
    __shared__ float Ws[F_IN * HDIM];   // [k][c] 32KB
    __shared__ float xs[64][65];        // padded node tile
    int t = threadIdx.x;
    const float4* W4 = (const float4*)W1;
    float4* Ws4 = (float4*)Ws;
    for (int i = t; i < F_IN * HDIM / 4; i += 256) Ws4[i] = W4[i];
    int row0 = blockIdx.x * 64;
    int c4 = t & 15, rg = t >> 4;
    float4 acc[4];
    #pragma unroll
    for (int i = 0; i < 4; ++i) acc[i] = make_float4(0.f, 0.f, 0.f, 0.f);
    const float4* x4 = (const float4*)x;
    for (int kc = 0; kc < 2; ++kc) {
        __syncthreads();
        for (int m = t; m < 1024; m += 256) {
            int n = m >> 4, k4 = m & 15;
            float4 v = make_float4(0.f, 0.f, 0.f, 0.f);
            int gn = row0 + n;
            if (gn < N_NODES) v = x4[gn * 32 + kc * 16 + k4];
            xs[n][k4 * 4 + 0] = v.x; xs[n][k4 * 4 + 1] = v.y;
            xs[n][k4 * 4 + 2] = v.z; xs[n][k4 * 4 + 3] = v.w;
        }
        __syncthreads();
        #pragma unroll 8
        for (int kk = 0; kk < 64; ++kk) {
            float4 wv = Ws4[(kc * 64 + kk) * 16 + c4];
            #pragma unroll
            for (int i = 0; i < 4; ++i) {
                float xv = xs[rg * 4 + i][kk];
                acc[i].x += wv.x * xv; acc[i].y += wv.y * xv;
                acc[i].z += wv.z * xv; acc[i].w += wv.w * xv;
            }
        }
    }
    float4* xwo = (float4*)xw;
    #pragma unroll
    for (int i = 0; i < 4; ++i) {
        int n = row0 + rg * 4 + i;
        if (n < N_NODES) xwo[n * 16 + c4] = acc[i];
    }
}

// ---------- tiled GEMM: xw2 = h1[50000,64] @ W2[64,64] ----------
__global__ __launch_bounds__(256) void conv2_k(const float* __restrict__ h1, const float* __restrict__ W2,
                                               float* __restrict__ xw2) {
    __shared__ float Ws[HDIM * HDIM];   // 16KB
    __shared__ float hs[64][65];
    int t = threadIdx.x;
    const float4* W4 = (const float4*)W2;
    float4* Ws4 = (float4*)Ws;
    for (int i = t; i < HDIM * HDIM / 4; i += 256) Ws4[i] = W4[i];
    int row0 = blockIdx.x * 64;
    const float4* h4 = (const float4*)h1;
    for (int m = t; m < 1024; m += 256) {
        int n = m >> 4, k4 = m & 15;
        float4 v = make_float4(0.f, 0.f, 0.f, 0.f);
        int gn = row0 + n;
        if (gn < N_NODES) v = h4[gn * 16 + k4];
        hs[n][k4 * 4 + 0] = v.x; hs[n][k4 * 4 + 1] = v.y;
        hs[n][k4 * 4 + 2] = v.z; hs[n][k4 * 4 + 3] = v.w;
    }
    __syncthreads();
    int c4 = t & 15, rg = t >> 4;
    float4 acc[4];
    #pragma unroll
    for (int i = 0; i < 4; ++i) acc[i] = make_float4(0.f, 0.f, 0.f, 0.f);
    #pragma unroll 8
    for (int kk = 0; kk < 64; ++kk) {
        float4 wv = Ws4[kk * 16 + c4];
        #pragma unroll
        for (int i = 0; i < 4; ++i) {
            float xv = hs[rg * 4 + i][kk];
            acc[i].x += wv.x * xv; acc[i].y += wv.y * xv;
            acc[i].z += wv.z * xv; acc[i].w += wv.w * xv;
        }
    }
    float4* xwo = (float4*)xw2;
    #pragma unroll
    for (int i = 0; i < 4; ++i) {
        int n = row0 + rg * 4 + i;
        if (n < N_NODES) xwo[n * 16 + c4] = acc[i];
    }
}

// ---------- gather: h[d] = relu(sum_{s in N(d)} xw[s]*dinv[s]*dinv[d] + xw[d]*dinv[d]^2 + b) ----------
// wave per node; 16 lanes x float4 per row; 4 edge slots in flight.
__device__ inline float4 xor_red(float4 v, int m) {
    v.x += __shfl_xor(v.x, m); v.y += __shfl_xor(v.y, m);
    v.z += __shfl_xor(v.z, m); v.w += __shfl_xor(v.w, m);
    return v;
}

__global__ __launch_bounds__(256) void gather_k(const float* __restrict__ xw, const int* __restrict__ row,
                                                const int* __restrict__ csr_src, const float* __restrict__ dinv,
                                                const float* __restrict__ bias, float* __restrict__ hout) {
    int t = threadIdx.x;
    int node = blockIdx.x * 4 + (t >> 6);
    int lane = t & 63;
    int eslot = lane >> 4, fq = lane & 15;
    const float4* xw4 = (const float4*)xw;
    float dd = dinv[node];
    float4 acc = make_float4(0.f, 0.f, 0.f, 0.f);
    if (eslot == 0) {
        float4 v = xw4[node * 16 + fq];
        float w = dd * dd;
        acc.x = v.x * w; acc.y = v.y * w; acc.z = v.z * w; acc.w = v.w * w;
    }
    int jend = row[node + 1];
    for (int j = row[node] + eslot; j < jend; j += 4) {
        int s = csr_src[j];
        float w = dinv[s] * dd;
        float4 v = xw4[s * 16 + fq];
        acc.x += v.x * w; acc.y += v.y * w; acc.z += v.z * w; acc.w += v.w * w;
    }
    acc = xor_red(acc, 16);
    acc = xor_red(acc, 32);
    if (eslot == 0) {
        float4 b = ((const float4*)bias)[fq];
        acc.x = fmaxf(acc.x + b.x, 0.f); acc.y = fmaxf(acc.y + b.y, 0.f);
        acc.z = fmaxf(acc.z + b.z, 0.f); acc.w = fmaxf(acc.w + b.w, 0.f);
        ((float4*)hout)[node * 16 + fq] = acc;
    }
}

// ---------- segmented mean-pool over sorted batch ----------
__device__ inline int lower_bound_i(const int* __restrict__ a, int n, int v) {
    int lo = 0, hi = n;
    while (lo < hi) { int m = (lo + hi) >> 1; if (a[m] < v) lo = m + 1; else hi = m; }
    return lo;
}

__global__ __launch_bounds__(256) void pool_k(const float* __restrict__ h, const int* __restrict__ batch,
                                              float* __restrict__ pooled) {
    __shared__ int se[2];
    __shared__ float red[4][64];
    int g = blockIdx.x, t = threadIdx.x;
    if (t == 0) { se[0] = lower_bound_i(batch, N_NODES, g); se[1] = lower_bound_i(batch, N_NODES, g + 1); }
    __syncthreads();
    int start = se[0], end = se[1];
    int w = t >> 6, lane = t & 63;
    float acc = 0.f;
    for (int n = start + w; n < end; n += 4) acc += h[n * 64 + lane];
    red[w][lane] = acc; __syncthreads();
    if (w == 0) {
        float v = red[0][lane] + red[1][lane] + red[2][lane] + red[3][lane];
        int c = end - start;
        pooled[g * 64 + lane] = v / (float)max(c, 1);
    }
}

// ---------- final MLP ----------
__global__ __launch_bounds__(128) void mlp_k(const float* __restrict__ pooled,
                                             const float* __restrict__ Wf1, const float* __restrict__ bf1,
                                             const float* __restrict__ Wf2, const float* __restrict__ bf2,
                                             float* __restrict__ out) {
    __shared__ float ps[HDIM];
    __shared__ float wsum[2];
    int g = blockIdx.x, t = threadIdx.x;
    if (t < HDIM) ps[t] = pooled[g * HDIM + t];
    __syncthreads();
    float acc = bf1[t];
    #pragma unroll 8
    for (int k = 0; k < HDIM; ++k) acc += ps[k] * Wf1[k * 128 + t];
    acc = fmaxf(acc, 0.f) * Wf2[t];
    #pragma unroll
    for (int off = 32; off > 0; off >>= 1) acc += __shfl_down(acc, off);
    if ((t & 63) == 0) wsum[t >> 6] = acc;
    __syncthreads();
    if (t == 0) out[g] = wsum[0] + wsum[1] + bf2[0];
}

extern "C" void kernel_launch(void* const* d_in, const int* in_sizes, int n_in,
                              void* d_out, int out_size, void* d_ws, size_t ws_size,
                              hipStream_t stream) {
    const float* x    = (const float*)d_in[0];
    const int*   ei   = (const int*)d_in[1];
    const int*   src  = ei;
    const int*   dst  = ei + N_EDGES;
    const int*   batch= (const int*)d_in[2];
    const float* W1   = (const float*)d_in[3];
    const float* b1   = (const float*)d_in[4];
    const float* W2   = (const float*)d_in[5];
    const float* b2   = (const float*)d_in[6];
    const float* Wf1  = (const float*)d_in[7];
    const float* bf1  = (const float*)d_in[8];
    const float* Wf2  = (const float*)d_in[9];
    const float* bf2  = (const float*)d_in[10];
    float* out = (float*)d_out;

    float* fws    = (float*)d_ws;
    float* xwbuf  = fws;                          // [N,64]
    float* hbuf   = xwbuf + N_NODES * HDIM;       // [N,64]
    float* dinv   = hbuf + N_NODES * HDIM;        // [N]
    float* pooled = dinv + N_NODES;               // [G,64]
    int*   cnt    = (int*)(pooled + N_GRAPHS * HDIM);  // [N]
    int*   row    = cnt + N_NODES;                // [N+1]
    int*   blksum = row + N_NODES + 1;            // [64]
    int*   cursor = blksum + 64;                  // [N]
    int*   csr    = cursor + N_NODES;             // [E]

    hipMemsetAsync(cnt, 0, N_NODES * sizeof(int), stream);
    count_k<<<(N_EDGES + 255) / 256, 256, 0, stream>>>(dst, cnt);
    scan1_k<<<N_SCAN_BLOCKS, 256, 0, stream>>>(cnt, row, blksum, dinv);
    scan2_k<<<1, 64, 0, stream>>>(blksum);
    scan3_k<<<(N_NODES + 255) / 256, 256, 0, stream>>>(row, blksum, cursor);
    fill_k<<<(N_EDGES + 255) / 256, 256, 0, stream>>>(src, dst, cursor, csr);

    xw1_k<<<(N_NODES + 63) / 64, 256, 0, stream>>>(x, W1, xwbuf);
    gather_k<<<N_NODES / 4, 256, 0, stream>>>(xwbuf, row, csr, dinv, b1, hbuf);
    conv2_k<<<(N_NODES + 63) / 64, 256, 0, stream>>>(hbuf, W2, xwbuf);
    gather_k<<<N_NODES / 4, 256, 0, stream>>>(xwbuf, row, csr, dinv, b2, hbuf);

    pool_k<<<N_GRAPHS, 256, 0, stream>>>(hbuf, batch, pooled);
    mlp_k<<<N_GRAPHS, 128, 0, stream>>>(pooled, Wf1, bf1, Wf2, bf2, out);
}

// Round 3
// 224.764 us; speedup vs baseline: 2.8649x; 1.3788x over previous
//
#include <hip/hip_runtime.h>
#include <hip/hip_fp16.h>

#define N_NODES 50000
#define N_EDGES 800000
#define N_GRAPHS 512
#define F_IN 128
#define HDIM 64
#define NBUCK 196            // ceil(50000/256) buckets of 256 nodes
#define BCAP 5120            // per-bucket staging capacity (avg 4082, max ~4400)
#define EPB 4096             // edges per pass-1 block
#define N_P1 ((N_EDGES + EPB - 1) / EPB)   // 196
#define MAXPER 20            // BCAP/256

// ---------------- pass 1: bin edges by dst bucket, dense staged writes ----------------
__global__ __launch_bounds__(256) void pass1_k(const int* __restrict__ src, const int* __restrict__ dst,
                                               int* __restrict__ bucketTot, int* __restrict__ stage) {
    __shared__ int cnt[256];
    __shared__ int goff[256];
    int t = threadIdx.x;
    cnt[t] = 0;
    __syncthreads();
    int base = blockIdx.x * EPB + t * 16;
    int packed[16], meta[16];
    bool full = (blockIdx.x + 1) * EPB <= N_EDGES;
    if (full) {
        const int4* s4 = (const int4*)(src + base);
        const int4* d4 = (const int4*)(dst + base);
        #pragma unroll
        for (int q = 0; q < 4; ++q) {
            int4 sv = s4[q], dv = d4[q];
            int ss[4] = {sv.x, sv.y, sv.z, sv.w};
            int dd[4] = {dv.x, dv.y, dv.z, dv.w};
            #pragma unroll
            for (int j = 0; j < 4; ++j) {
                int b = dd[j] >> 8;
                int r = atomicAdd(&cnt[b], 1);
                packed[q * 4 + j] = ss[j] | ((dd[j] & 255) << 16);
                meta[q * 4 + j] = r | (b << 16);
            }
        }
    } else {
        #pragma unroll
        for (int k = 0; k < 16; ++k) {
            int e = base + k;
            if (e < N_EDGES) {
                int d = dst[e];
                int b = d >> 8;
                int r = atomicAdd(&cnt[b], 1);
                packed[k] = src[e] | ((d & 255) << 16);
                meta[k] = r | (b << 16);
            } else meta[k] = -1;
        }
    }
    __syncthreads();
    if (cnt[t] > 0) goff[t] = atomicAdd(&bucketTot[t], cnt[t]);
    __syncthreads();
    #pragma unroll
    for (int k = 0; k < 16; ++k) {
        if (meta[k] >= 0) {
            int b = meta[k] >> 16, r = meta[k] & 0xFFFF;
            stage[b * BCAP + goff[b] + r] = packed[k];
        }
    }
}

// ---------------- scan bucket totals -> bases ----------------
__global__ __launch_bounds__(256) void scanB_k(const int* __restrict__ bucketTot, int* __restrict__ bucketBase,
                                               int* __restrict__ row) {
    __shared__ int s[256];
    int t = threadIdx.x;
    int v = (t < NBUCK) ? bucketTot[t] : 0;
    s[t] = v; __syncthreads();
    for (int off = 1; off < 256; off <<= 1) {
        int u = (t >= off) ? s[t - off] : 0; __syncthreads();
        s[t] += u; __syncthreads();
    }
    if (t < NBUCK) bucketBase[t] = s[t] - v;   // exclusive
    if (t == 0) row[N_NODES] = N_EDGES;
}

// ---------------- pass 2: per-bucket LDS counting sort -> csr, row, dinv ----------------
__global__ __launch_bounds__(256) void pass2_k(const int* __restrict__ stage, const int* __restrict__ bucketTot,
                                               const int* __restrict__ bucketBase, int* __restrict__ row,
                                               float* __restrict__ dinv, int* __restrict__ csr) {
    __shared__ int cnt[256];
    __shared__ int pf[256];
    __shared__ int lcsr[BCAP];
    int b = blockIdx.x, t = threadIdx.x;
    int tot = bucketTot[b], base = bucketBase[b];
    cnt[t] = 0; __syncthreads();
    int myp[MAXPER], myr[MAXPER];
    #pragma unroll
    for (int k = 0; k < MAXPER; ++k) {
        int i = t + k * 256;
        if (i < tot) {
            int p = stage[b * BCAP + i];
            int loc = (p >> 16) & 255;
            myp[k] = p;
            myr[k] = atomicAdd(&cnt[loc], 1);
        } else myp[k] = -1;
    }
    __syncthreads();
    int cv = cnt[t];
    pf[t] = cv; __syncthreads();
    for (int off = 1; off < 256; off <<= 1) {
        int u = (t >= off) ? pf[t - off] : 0; __syncthreads();
        pf[t] += u; __syncthreads();
    }
    int node = b * 256 + t;
    if (node < N_NODES) {
        row[node] = base + pf[t] - cv;          // exclusive prefix
        dinv[node] = rsqrtf((float)cv + 1.0f);  // deg incl self-loop
    }
    #pragma unroll
    for (int k = 0; k < MAXPER; ++k) {
        if (myp[k] >= 0) {
            int loc = (myp[k] >> 16) & 255;
            lcsr[pf[loc] - cnt[loc] + myr[k]] = myp[k] & 0xFFFF;
        }
    }
    __syncthreads();
    for (int i = t; i < tot; i += 256) csr[base + i] = lcsr[i];
}

// ---------------- xw1 = (x @ W1) * dinv  -> fp16 ----------------
__global__ __launch_bounds__(256) void xw1_k(const float* __restrict__ x, const float* __restrict__ W1,
                                             const float* __restrict__ dinv, __half* __restrict__ xwh) {
    __shared__ float Ws[F_IN * HDIM];   // 32KB
    __shared__ float xs[64][65];
    int t = threadIdx.x;
    const float4* W4 = (const float4*)W1;
    float4* Ws4 = (float4*)Ws;
    for (int i = t; i < F_IN * HDIM / 4; i += 256) Ws4[i] = W4[i];
    int row0 = blockIdx.x * 64;
    int c4 = t & 15, rg = t >> 4;
    float4 acc[4];
    #pragma unroll
    for (int i = 0; i < 4; ++i) acc[i] = make_float4(0.f, 0.f, 0.f, 0.f);
    const float4* x4 = (const float4*)x;
    for (int kc = 0; kc < 2; ++kc) {
        __syncthreads();
        for (int m = t; m < 1024; m += 256) {
            int n = m >> 4, k4 = m & 15;
            float4 v = make_float4(0.f, 0.f, 0.f, 0.f);
            int gn = row0 + n;
            if (gn < N_NODES) v = x4[gn * 32 + kc * 16 + k4];
            xs[n][k4 * 4 + 0] = v.x; xs[n][k4 * 4 + 1] = v.y;
            xs[n][k4 * 4 + 2] = v.z; xs[n][k4 * 4 + 3] = v.w;
        }
        __syncthreads();
        #pragma unroll 8
        for (int kk = 0; kk < 64; ++kk) {
            float4 wv = Ws4[(kc * 64 + kk) * 16 + c4];
            #pragma unroll
            for (int i = 0; i < 4; ++i) {
                float xv = xs[rg * 4 + i][kk];
                acc[i].x += wv.x * xv; acc[i].y += wv.y * xv;
                acc[i].z += wv.z * xv; acc[i].w += wv.w * xv;
            }
        }
    }
    uint2* xo = (uint2*)xwh;
    #pragma unroll
    for (int i = 0; i < 4; ++i) {
        int n = row0 + rg * 4 + i;
        if (n < N_NODES) {
            float dv = dinv[n];
            __half2 p0 = __float22half2_rn(make_float2(acc[i].x * dv, acc[i].y * dv));
            __half2 p1 = __float22half2_rn(make_float2(acc[i].z * dv, acc[i].w * dv));
            uint2 o;
            o.x = __builtin_bit_cast(unsigned int, p0);
            o.y = __builtin_bit_cast(unsigned int, p1);
            xo[n * 16 + c4] = o;
        }
    }
}

// ---------------- xw2 = (h1 @ W2) * dinv -> fp16 ----------------
__global__ __launch_bounds__(256) void conv2_k(const float* __restrict__ h1, const float* __restrict__ W2,
                                               const float* __restrict__ dinv, __half* __restrict__ xwh) {
    __shared__ float Ws[HDIM * HDIM];
    __shared__ float hs[64][65];
    int t = threadIdx.x;
    const float4* W4 = (const float4*)W2;
    float4* Ws4 = (float4*)Ws;
    for (int i = t; i < HDIM * HDIM / 4; i += 256) Ws4[i] = W4[i];
    int row0 = blockIdx.x * 64;
    const float4* h4 = (const float4*)h1;
    for (int m = t; m < 1024; m += 256) {
        int n = m >> 4, k4 = m & 15;
        float4 v = make_float4(0.f, 0.f, 0.f, 0.f);
        int gn = row0 + n;
        if (gn < N_NODES) v = h4[gn * 16 + k4];
        hs[n][k4 * 4 + 0] = v.x; hs[n][k4 * 4 + 1] = v.y;
        hs[n][k4 * 4 + 2] = v.z; hs[n][k4 * 4 + 3] = v.w;
    }
    __syncthreads();
    int c4 = t & 15, rg = t >> 4;
    float4 acc[4];
    #pragma unroll
    for (int i = 0; i < 4; ++i) acc[i] = make_float4(0.f, 0.f, 0.f, 0.f);
    #pragma unroll 8
    for (int kk = 0; kk < 64; ++kk) {
        float4 wv = Ws4[kk * 16 + c4];
        #pragma unroll
        for (int i = 0; i < 4; ++i) {
            float xv = hs[rg * 4 + i][kk];
            acc[i].x += wv.x * xv; acc[i].y += wv.y * xv;
            acc[i].z += wv.z * xv; acc[i].w += wv.w * xv;
        }
    }
    uint2* xo = (uint2*)xwh;
    #pragma unroll
    for (int i = 0; i < 4; ++i) {
        int n = row0 + rg * 4 + i;
        if (n < N_NODES) {
            float dv = dinv[n];
            __half2 p0 = __float22half2_rn(make_float2(acc[i].x * dv, acc[i].y * dv));
            __half2 p1 = __float22half2_rn(make_float2(acc[i].z * dv, acc[i].w * dv));
            uint2 o;
            o.x = __builtin_bit_cast(unsigned int, p0);
            o.y = __builtin_bit_cast(unsigned int, p1);
            xo[n * 16 + c4] = o;
        }
    }
}

// ---------------- gather: h[d] = relu(dinv[d] * (sum xwh[s] + xwh[d]) + b) ----------------
__device__ inline void acc8(uint4 v, float* a) {
    float2 f;
    f = __half22float2(__builtin_bit_cast(__half2, v.x)); a[0] += f.x; a[1] += f.y;
    f = __half22float2(__builtin_bit_cast(__half2, v.y)); a[2] += f.x; a[3] += f.y;
    f = __half22float2(__builtin_bit_cast(__half2, v.z)); a[4] += f.x; a[5] += f.y;
    f = __half22float2(__builtin_bit_cast(__half2, v.w)); a[6] += f.x; a[7] += f.y;
}

__global__ __launch_bounds__(256) void gather_k(const __half* __restrict__ xwh, const int* __restrict__ row,
                                                const int* __restrict__ csr, const float* __restrict__ dinv,
                                                const float* __restrict__ bias, float* __restrict__ hout) {
    int t = threadIdx.x;
    int node = blockIdx.x * 4 + (t >> 6);
    int lane = t & 63;
    int fq = lane & 7, eslot = lane >> 3;   // 8 feature-groups x 8 edge slots
    const uint4* xw4 = (const uint4*)xwh;
    float a[8];
    #pragma unroll
    for (int k = 0; k < 8; ++k) a[k] = 0.f;
    if (eslot == 0) { uint4 v = xw4[node * 8 + fq]; acc8(v, a); }   // self-loop
    int jend = row[node + 1];
    for (int j = row[node] + eslot; j < jend; j += 8) {
        int s = csr[j];
        uint4 v = xw4[s * 8 + fq];
        acc8(v, a);
    }
    #pragma unroll
    for (int k = 0; k < 8; ++k) {
        a[k] += __shfl_xor(a[k], 8);
        a[k] += __shfl_xor(a[k], 16);
        a[k] += __shfl_xor(a[k], 32);
    }
    if (eslot == 0) {
        float dd = dinv[node];
        const float4* b4 = (const float4*)bias;
        float4 bl = b4[fq * 2], bh = b4[fq * 2 + 1];
        float4 o0, o1;
        o0.x = fmaxf(a[0] * dd + bl.x, 0.f); o0.y = fmaxf(a[1] * dd + bl.y, 0.f);
        o0.z = fmaxf(a[2] * dd + bl.z, 0.f); o0.w = fmaxf(a[3] * dd + bl.w, 0.f);
        o1.x = fmaxf(a[4] * dd + bh.x, 0.f); o1.y = fmaxf(a[5] * dd + bh.y, 0.f);
        o1.z = fmaxf(a[6] * dd + bh.z, 0.f); o1.w = fmaxf(a[7] * dd + bh.w, 0.f);
        float4* ho = (float4*)hout;
        ho[node * 16 + fq * 2] = o0;
        ho[node * 16 + fq * 2 + 1] = o1;
    }
}

// ---------------- segmented mean-pool ----------------
__device__ inline int lower_bound_i(const int* __restrict__ a, int n, int v) {
    int lo = 0, hi = n;
    while (lo < hi) { int m = (lo + hi) >> 1; if (a[m] < v) lo = m + 1; else hi = m; }
    return lo;
}

__global__ __launch_bounds__(256) void pool_k(const float* __restrict__ h, const int* __restrict__ batch,
                                              float* __restrict__ pooled) {
    __shared__ int se[2];
    __shared__ float red[4][64];
    int g = blockIdx.x, t = threadIdx.x;
    if (t == 0) { se[0] = lower_bound_i(batch, N_NODES, g); se[1] = lower_bound_i(batch, N_NODES, g + 1); }
    __syncthreads();
    int start = se[0], end = se[1];
    int w = t >> 6, lane = t & 63;
    float acc = 0.f;
    for (int n = start + w; n < end; n += 4) acc += h[n * 64 + lane];
    red[w][lane] = acc; __syncthreads();
    if (w == 0) {
        float v = red[0][lane] + red[1][lane] + red[2][lane] + red[3][lane];
        int c = end - start;
        pooled[g * 64 + lane] = v / (float)max(c, 1);
    }
}

// ---------------- final MLP ----------------
__global__ __launch_bounds__(128) void mlp_k(const float* __restrict__ pooled,
                                             const float* __restrict__ Wf1, const float* __restrict__ bf1,
                                             const float* __restrict__ Wf2, const float* __restrict__ bf2,
                                             float* __restrict__ out) {
    __shared__ float ps[HDIM];
    __shared__ float wsum[2];
    int g = blockIdx.x, t = threadIdx.x;
    if (t < HDIM) ps[t] = pooled[g * HDIM + t];
    __syncthreads();
    float acc = bf1[t];
    #pragma unroll 8
    for (int k = 0; k < HDIM; ++k) acc += ps[k] * Wf1[k * 128 + t];
    acc = fmaxf(acc, 0.f) * Wf2[t];
    #pragma unroll
    for (int off = 32; off > 0; off >>= 1) acc += __shfl_down(acc, off);
    if ((t & 63) == 0) wsum[t >> 6] = acc;
    __syncthreads();
    if (t == 0) out[g] = wsum[0] + wsum[1] + bf2[0];
}

extern "C" void kernel_launch(void* const* d_in, const int* in_sizes, int n_in,
                              void* d_out, int out_size, void* d_ws, size_t ws_size,
                              hipStream_t stream) {
    const float* x    = (const float*)d_in[0];
    const int*   ei   = (const int*)d_in[1];
    const int*   src  = ei;
    const int*   dst  = ei + N_EDGES;
    const int*   batch= (const int*)d_in[2];
    const float* W1   = (const float*)d_in[3];
    const float* b1   = (const float*)d_in[4];
    const float* W2   = (const float*)d_in[5];
    const float* b2   = (const float*)d_in[6];
    const float* Wf1  = (const float*)d_in[7];
    const float* bf1  = (const float*)d_in[8];
    const float* Wf2  = (const float*)d_in[9];
    const float* bf2  = (const float*)d_in[10];
    float* out = (float*)d_out;

    char* p = (char*)d_ws;
    float*  hbuf   = (float*)p;   p += (size_t)N_NODES * HDIM * 4;
    __half* xwh    = (__half*)p;  p += (size_t)N_NODES * HDIM * 2;
    float*  dinv   = (float*)p;   p += (size_t)N_NODES * 4;
    float*  pooled = (float*)p;   p += (size_t)N_GRAPHS * HDIM * 4;
    int*    row    = (int*)p;     p += (size_t)(N_NODES + 1) * 4;
    int*    csr    = (int*)p;     p += (size_t)N_EDGES * 4;
    int*    bTot   = (int*)p;     p += 256 * 4;
    int*    bBase  = (int*)p;     p += 256 * 4;
    int*    stage  = (int*)p;     p += (size_t)NBUCK * BCAP * 4;

    hipMemsetAsync(bTot, 0, 256 * 4, stream);
    pass1_k<<<N_P1, 256, 0, stream>>>(src, dst, bTot, stage);
    scanB_k<<<1, 256, 0, stream>>>(bTot, bBase, row);
    pass2_k<<<NBUCK, 256, 0, stream>>>(stage, bTot, bBase, row, dinv, csr);

    xw1_k<<<(N_NODES + 63) / 64, 256, 0, stream>>>(x, W1, dinv, xwh);
    gather_k<<<N_NODES / 4, 256, 0, stream>>>(xwh, row, csr, dinv, b1, hbuf);
    conv2_k<<<(N_NODES + 63) / 64, 256, 0, stream>>>(hbuf, W2, dinv, xwh);
    gather_k<<<N_NODES / 4, 256, 0, stream>>>(xwh, row, csr, dinv, b2, hbuf);

    pool_k<<<N_GRAPHS, 256, 0, stream>>>(hbuf, batch, pooled);
    mlp_k<<<N_GRAPHS, 128, 0, stream>>>(pooled, Wf1, bf1, Wf2, bf2, out);
}

// Round 4
// 219.821 us; speedup vs baseline: 2.9293x; 1.0225x over previous
//
#include <hip/hip_runtime.h>
#include <hip/hip_fp16.h>

#define N_NODES 50000
#define N_EDGES 800000
#define N_GRAPHS 512
#define F_IN 128
#define HDIM 64
#define NBUCK 196            // ceil(50000/256) buckets of 256 nodes
#define BCAP 5120            // per-bucket staging capacity (avg 4082)
#define EPB 4096             // edges per pass-1 block
#define N_P1 ((N_EDGES + EPB - 1) / EPB)   // 196
#define MAXPER 20            // BCAP/256

// ---------------- pass 1: bin edges by dst bucket; LDS counting sort -> coalesced writes ----------------
__global__ __launch_bounds__(256) void pass1_k(const int* __restrict__ src, const int* __restrict__ dst,
                                               int* __restrict__ bucketTot, int* __restrict__ stage) {
    __shared__ int cnt[256];
    __shared__ int pf[256];
    __shared__ int goff[256];
    __shared__ int lpk[EPB];               // bucket-ordered packed edges (16KB)
    __shared__ unsigned char bkn[EPB];     // bucket id per slot (4KB)
    int t = threadIdx.x;
    cnt[t] = 0;
    __syncthreads();
    int base = blockIdx.x * EPB + t * 16;
    int packed[16], bk[16], rk[16];
    bool full = (blockIdx.x + 1) * EPB <= N_EDGES;
    if (full) {
        const int4* s4 = (const int4*)(src + base);
        const int4* d4 = (const int4*)(dst + base);
        #pragma unroll
        for (int q = 0; q < 4; ++q) {
            int4 sv = s4[q], dv = d4[q];
            int ss[4] = {sv.x, sv.y, sv.z, sv.w};
            int dd[4] = {dv.x, dv.y, dv.z, dv.w};
            #pragma unroll
            for (int j = 0; j < 4; ++j) {
                int b = dd[j] >> 8;
                rk[q * 4 + j] = atomicAdd(&cnt[b], 1);
                bk[q * 4 + j] = b;
                packed[q * 4 + j] = ss[j] | ((dd[j] & 255) << 16);
            }
        }
    } else {
        #pragma unroll
        for (int k = 0; k < 16; ++k) {
            int e = base + k;
            if (e < N_EDGES) {
                int d = dst[e];
                int b = d >> 8;
                rk[k] = atomicAdd(&cnt[b], 1);
                bk[k] = b;
                packed[k] = src[e] | ((d & 255) << 16);
            } else bk[k] = -1;
        }
    }
    __syncthreads();
    int cv = cnt[t];
    pf[t] = cv; __syncthreads();
    for (int off = 1; off < 256; off <<= 1) {
        int u = (t >= off) ? pf[t - off] : 0; __syncthreads();
        pf[t] += u; __syncthreads();
    }
    if (cv > 0) goff[t] = atomicAdd(&bucketTot[t], cv);
    // scatter into bucket-ordered LDS
    #pragma unroll
    for (int k = 0; k < 16; ++k) {
        if (bk[k] >= 0) {
            int b = bk[k];
            int p = pf[b] - cnt[b] + rk[k];
            lpk[p] = packed[k];
            bkn[p] = (unsigned char)b;
        }
    }
    __syncthreads();
    int tot = pf[255];
    // coalesced write-out: consecutive i within a bucket -> consecutive global slots
    for (int i = t; i < tot; i += 256) {
        int b = bkn[i];
        int local = i - (pf[b] - cnt[b]);
        stage[b * BCAP + goff[b] + local] = lpk[i];
    }
}

// ---------------- scan bucket totals -> bases ----------------
__global__ __launch_bounds__(256) void scanB_k(const int* __restrict__ bucketTot, int* __restrict__ bucketBase,
                                               int* __restrict__ row) {
    __shared__ int s[256];
    int t = threadIdx.x;
    int v = (t < NBUCK) ? bucketTot[t] : 0;
    s[t] = v; __syncthreads();
    for (int off = 1; off < 256; off <<= 1) {
        int u = (t >= off) ? s[t - off] : 0; __syncthreads();
        s[t] += u; __syncthreads();
    }
    if (t < NBUCK) bucketBase[t] = s[t] - v;   // exclusive
    if (t == 0) row[N_NODES] = N_EDGES;
}

// ---------------- pass 2: per-bucket LDS counting sort -> csr, row, dinv ----------------
__global__ __launch_bounds__(256) void pass2_k(const int* __restrict__ stage, const int* __restrict__ bucketTot,
                                               const int* __restrict__ bucketBase, int* __restrict__ row,
                                               float* __restrict__ dinv, int* __restrict__ csr) {
    __shared__ int cnt[256];
    __shared__ int pf[256];
    __shared__ int lcsr[BCAP];
    int b = blockIdx.x, t = threadIdx.x;
    int tot = bucketTot[b], base = bucketBase[b];
    cnt[t] = 0; __syncthreads();
    int myp[MAXPER], myr[MAXPER];
    #pragma unroll
    for (int k = 0; k < MAXPER; ++k) {
        int i = t + k * 256;
        if (i < tot) {
            int p = stage[b * BCAP + i];
            int loc = (p >> 16) & 255;
            myp[k] = p;
            myr[k] = atomicAdd(&cnt[loc], 1);
        } else myp[k] = -1;
    }
    __syncthreads();
    int cv = cnt[t];
    pf[t] = cv; __syncthreads();
    for (int off = 1; off < 256; off <<= 1) {
        int u = (t >= off) ? pf[t - off] : 0; __syncthreads();
        pf[t] += u; __syncthreads();
    }
    int node = b * 256 + t;
    if (node < N_NODES) {
        row[node] = base + pf[t] - cv;
        dinv[node] = rsqrtf((float)cv + 1.0f);
    }
    #pragma unroll
    for (int k = 0; k < MAXPER; ++k) {
        if (myp[k] >= 0) {
            int loc = (myp[k] >> 16) & 255;
            lcsr[pf[loc] - cnt[loc] + myr[k]] = myp[k] & 0xFFFF;
        }
    }
    __syncthreads();
    for (int i = t; i < tot; i += 256) csr[base + i] = lcsr[i];
}

// ---------------- xw1 = (x @ W1) * dinv  -> fp16 ----------------
__global__ __launch_bounds__(256) void xw1_k(const float* __restrict__ x, const float* __restrict__ W1,
                                             const float* __restrict__ dinv, __half* __restrict__ xwh) {
    __shared__ float Ws[F_IN * HDIM];   // 32KB
    __shared__ float xs[64][65];
    int t = threadIdx.x;
    const float4* W4 = (const float4*)W1;
    float4* Ws4 = (float4*)Ws;
    for (int i = t; i < F_IN * HDIM / 4; i += 256) Ws4[i] = W4[i];
    int row0 = blockIdx.x * 64;
    int c4 = t & 15, rg = t >> 4;
    float4 acc[4];
    #pragma unroll
    for (int i = 0; i < 4; ++i) acc[i] = make_float4(0.f, 0.f, 0.f, 0.f);
    const float4* x4 = (const float4*)x;
    for (int kc = 0; kc < 2; ++kc) {
        __syncthreads();
        for (int m = t; m < 1024; m += 256) {
            int n = m >> 4, k4 = m & 15;
            float4 v = make_float4(0.f, 0.f, 0.f, 0.f);
            int gn = row0 + n;
            if (gn < N_NODES) v = x4[gn * 32 + kc * 16 + k4];
            xs[n][k4 * 4 + 0] = v.x; xs[n][k4 * 4 + 1] = v.y;
            xs[n][k4 * 4 + 2] = v.z; xs[n][k4 * 4 + 3] = v.w;
        }
        __syncthreads();
        #pragma unroll 8
        for (int kk = 0; kk < 64; ++kk) {
            float4 wv = Ws4[(kc * 64 + kk) * 16 + c4];
            #pragma unroll
            for (int i = 0; i < 4; ++i) {
                float xv = xs[rg * 4 + i][kk];
                acc[i].x += wv.x * xv; acc[i].y += wv.y * xv;
                acc[i].z += wv.z * xv; acc[i].w += wv.w * xv;
            }
        }
    }
    uint2* xo = (uint2*)xwh;
    #pragma unroll
    for (int i = 0; i < 4; ++i) {
        int n = row0 + rg * 4 + i;
        if (n < N_NODES) {
            float dv = dinv[n];
            __half2 p0 = __float22half2_rn(make_float2(acc[i].x * dv, acc[i].y * dv));
            __half2 p1 = __float22half2_rn(make_float2(acc[i].z * dv, acc[i].w * dv));
            uint2 o;
            o.x = __builtin_bit_cast(unsigned int, p0);
            o.y = __builtin_bit_cast(unsigned int, p1);
            xo[n * 16 + c4] = o;
        }
    }
}

// ---------------- xw2 = (h1 @ W2) * dinv -> fp16   (h1 itself fp16) ----------------
__global__ __launch_bounds__(256) void conv2_k(const __half* __restrict__ h1, const float* __restrict__ W2,
                                               const float* __restrict__ dinv, __half* __restrict__ xwh) {
    __shared__ float Ws[HDIM * HDIM];
    __shared__ float hs[64][65];
    int t = threadIdx.x;
    const float4* W4 = (const float4*)W2;
    float4* Ws4 = (float4*)Ws;
    for (int i = t; i < HDIM * HDIM / 4; i += 256) Ws4[i] = W4[i];
    int row0 = blockIdx.x * 64;
    const uint4* h8 = (const uint4*)h1;
    for (int m = t; m < 512; m += 256) {
        int n = m >> 3, k8 = m & 7;
        int gn = row0 + n;
        uint4 v = make_uint4(0u, 0u, 0u, 0u);
        if (gn < N_NODES) v = h8[gn * 8 + k8];
        float2 f0 = __half22float2(__builtin_bit_cast(__half2, v.x));
        float2 f1 = __half22float2(__builtin_bit_cast(__half2, v.y));
        float2 f2 = __half22float2(__builtin_bit_cast(__half2, v.z));
        float2 f3 = __half22float2(__builtin_bit_cast(__half2, v.w));
        float* hp = &hs[n][k8 * 8];
        hp[0] = f0.x; hp[1] = f0.y; hp[2] = f1.x; hp[3] = f1.y;
        hp[4] = f2.x; hp[5] = f2.y; hp[6] = f3.x; hp[7] = f3.y;
    }
    __syncthreads();
    int c4 = t & 15, rg = t >> 4;
    float4 acc[4];
    #pragma unroll
    for (int i = 0; i < 4; ++i) acc[i] = make_float4(0.f, 0.f, 0.f, 0.f);
    #pragma unroll 8
    for (int kk = 0; kk < 64; ++kk) {
        float4 wv = Ws4[kk * 16 + c4];
        #pragma unroll
        for (int i = 0; i < 4; ++i) {
            float xv = hs[rg * 4 + i][kk];
            acc[i].x += wv.x * xv; acc[i].y += wv.y * xv;
            acc[i].z += wv.z * xv; acc[i].w += wv.w * xv;
        }
    }
    uint2* xo = (uint2*)xwh;
    #pragma unroll
    for (int i = 0; i < 4; ++i) {
        int n = row0 + rg * 4 + i;
        if (n < N_NODES) {
            float dv = dinv[n];
            __half2 p0 = __float22half2_rn(make_float2(acc[i].x * dv, acc[i].y * dv));
            __half2 p1 = __float22half2_rn(make_float2(acc[i].z * dv, acc[i].w * dv));
            uint2 o;
            o.x = __builtin_bit_cast(unsigned int, p0);
            o.y = __builtin_bit_cast(unsigned int, p1);
            xo[n * 16 + c4] = o;
        }
    }
}

// ---------------- gather: h[d] = relu(dinv[d] * (sum xwh[s] + xwh[d]) + b) ----------------
__device__ inline void acc8(uint4 v, float* a) {
    float2 f;
    f = __half22float2(__builtin_bit_cast(__half2, v.x)); a[0] += f.x; a[1] += f.y;
    f = __half22float2(__builtin_bit_cast(__half2, v.y)); a[2] += f.x; a[3] += f.y;
    f = __half22float2(__builtin_bit_cast(__half2, v.z)); a[4] += f.x; a[5] += f.y;
    f = __half22float2(__builtin_bit_cast(__half2, v.w)); a[6] += f.x; a[7] += f.y;
}

template <bool OUT_HALF>
__global__ __launch_bounds__(256) void gather_k(const __half* __restrict__ xwh, const int* __restrict__ row,
                                                const int* __restrict__ csr, const float* __restrict__ dinv,
                                                const float* __restrict__ bias, void* __restrict__ hout) {
    int t = threadIdx.x;
    int node = blockIdx.x * 4 + (t >> 6);
    int lane = t & 63;
    int fq = lane & 7, eslot = lane >> 3;   // 8 feature-groups x 8 edge slots
    const uint4* xw4 = (const uint4*)xwh;
    float a[8];
    #pragma unroll
    for (int k = 0; k < 8; ++k) a[k] = 0.f;
    if (eslot == 0) { uint4 v = xw4[node * 8 + fq]; acc8(v, a); }   // self-loop
    int jend = row[node + 1];
    for (int j = row[node] + eslot; j < jend; j += 8) {
        int s = csr[j];
        uint4 v = xw4[s * 8 + fq];
        acc8(v, a);
    }
    #pragma unroll
    for (int k = 0; k < 8; ++k) {
        a[k] += __shfl_xor(a[k], 8);
        a[k] += __shfl_xor(a[k], 16);
        a[k] += __shfl_xor(a[k], 32);
    }
    if (eslot == 0) {
        float dd = dinv[node];
        const float4* b4 = (const float4*)bias;
        float4 bl = b4[fq * 2], bh = b4[fq * 2 + 1];
        float r[8];
        r[0] = fmaxf(a[0] * dd + bl.x, 0.f); r[1] = fmaxf(a[1] * dd + bl.y, 0.f);
        r[2] = fmaxf(a[2] * dd + bl.z, 0.f); r[3] = fmaxf(a[3] * dd + bl.w, 0.f);
        r[4] = fmaxf(a[4] * dd + bh.x, 0.f); r[5] = fmaxf(a[5] * dd + bh.y, 0.f);
        r[6] = fmaxf(a[6] * dd + bh.z, 0.f); r[7] = fmaxf(a[7] * dd + bh.w, 0.f);
        if (OUT_HALF) {
            __half2 p0 = __float22half2_rn(make_float2(r[0], r[1]));
            __half2 p1 = __float22half2_rn(make_float2(r[2], r[3]));
            __half2 p2 = __float22half2_rn(make_float2(r[4], r[5]));
            __half2 p3 = __float22half2_rn(make_float2(r[6], r[7]));
            uint4 o;
            o.x = __builtin_bit_cast(unsigned int, p0);
            o.y = __builtin_bit_cast(unsigned int, p1);
            o.z = __builtin_bit_cast(unsigned int, p2);
            o.w = __builtin_bit_cast(unsigned int, p3);
            ((uint4*)hout)[node * 8 + fq] = o;
        } else {
            float4* ho = (float4*)hout;
            ho[node * 16 + fq * 2]     = make_float4(r[0], r[1], r[2], r[3]);
            ho[node * 16 + fq * 2 + 1] = make_float4(r[4], r[5], r[6], r[7]);
        }
    }
}

// ---------------- segmented mean-pool ----------------
__device__ inline int lower_bound_i(const int* __restrict__ a, int n, int v) {
    int lo = 0, hi = n;
    while (lo < hi) { int m = (lo + hi) >> 1; if (a[m] < v) lo = m + 1; else hi = m; }
    return lo;
}

__global__ __launch_bounds__(256) void pool_k(const float* __restrict__ h, const int* __restrict__ batch,
                                              float* __restrict__ pooled) {
    __shared__ int se[2];
    __shared__ float red[4][64];
    int g = blockIdx.x, t = threadIdx.x;
    if (t == 0) { se[0] = lower_bound_i(batch, N_NODES, g); se[1] = lower_bound_i(batch, N_NODES, g + 1); }
    __syncthreads();
    int start = se[0], end = se[1];
    int w = t >> 6, lane = t & 63;
    float acc = 0.f;
    for (int n = start + w; n < end; n += 4) acc += h[n * 64 + lane];
    red[w][lane] = acc; __syncthreads();
    if (w == 0) {
        float v = red[0][lane] + red[1][lane] + red[2][lane] + red[3][lane];
        int c = end - start;
        pooled[g * 64 + lane] = v / (float)max(c, 1);
    }
}

// ---------------- final MLP ----------------
__global__ __launch_bounds__(128) void mlp_k(const float* __restrict__ pooled,
                                             const float* __restrict__ Wf1, const float* __restrict__ bf1,
                                             const float* __restrict__ Wf2, const float* __restrict__ bf2,
                                             float* __restrict__ out) {
    __shared__ float ps[HDIM];
    __shared__ float wsum[2];
    int g = blockIdx.x, t = threadIdx.x;
    if (t < HDIM) ps[t] = pooled[g * HDIM + t];
    __syncthreads();
    float acc = bf1[t];
    #pragma unroll 8
    for (int k = 0; k < HDIM; ++k) acc += ps[k] * Wf1[k * 128 + t];
    acc = fmaxf(acc, 0.f) * Wf2[t];
    #pragma unroll
    for (int off = 32; off > 0; off >>= 1) acc += __shfl_down(acc, off);
    if ((t & 63) == 0) wsum[t >> 6] = acc;
    __syncthreads();
    if (t == 0) out[g] = wsum[0] + wsum[1] + bf2[0];
}

extern "C" void kernel_launch(void* const* d_in, const int* in_sizes, int n_in,
                              void* d_out, int out_size, void* d_ws, size_t ws_size,
                              hipStream_t stream) {
    const float* x    = (const float*)d_in[0];
    const int*   ei   = (const int*)d_in[1];
    const int*   src  = ei;
    const int*   dst  = ei + N_EDGES;
    const int*   batch= (const int*)d_in[2];
    const float* W1   = (const float*)d_in[3];
    const float* b1   = (const float*)d_in[4];
    const float* W2   = (const float*)d_in[5];
    const float* b2   = (const float*)d_in[6];
    const float* Wf1  = (const float*)d_in[7];
    const float* bf1  = (const float*)d_in[8];
    const float* Wf2  = (const float*)d_in[9];
    const float* bf2  = (const float*)d_in[10];
    float* out = (float*)d_out;

    char* p = (char*)d_ws;
    float*  h2buf  = (float*)p;   p += (size_t)N_NODES * HDIM * 4;   // h2 fp32
    __half* h1buf  = (__half*)p;  p += (size_t)N_NODES * HDIM * 2;   // h1 fp16
    __half* xwh    = (__half*)p;  p += (size_t)N_NODES * HDIM * 2;
    float*  dinv   = (float*)p;   p += (size_t)N_NODES * 4;
    float*  pooled = (float*)p;   p += (size_t)N_GRAPHS * HDIM * 4;
    int*    row    = (int*)p;     p += (size_t)(N_NODES + 1) * 4;
    int*    csr    = (int*)p;     p += (size_t)N_EDGES * 4;
    int*    bTot   = (int*)p;     p += 256 * 4;
    int*    bBase  = (int*)p;     p += 256 * 4;
    int*    stage  = (int*)p;     p += (size_t)NBUCK * BCAP * 4;

    hipMemsetAsync(bTot, 0, 256 * 4, stream);
    pass1_k<<<N_P1, 256, 0, stream>>>(src, dst, bTot, stage);
    scanB_k<<<1, 256, 0, stream>>>(bTot, bBase, row);
    pass2_k<<<NBUCK, 256, 0, stream>>>(stage, bTot, bBase, row, dinv, csr);

    xw1_k<<<(N_NODES + 63) / 64, 256, 0, stream>>>(x, W1, dinv, xwh);
    gather_k<true><<<N_NODES / 4, 256, 0, stream>>>(xwh, row, csr, dinv, b1, (void*)h1buf);
    conv2_k<<<(N_NODES + 63) / 64, 256, 0, stream>>>(h1buf, W2, dinv, xwh);
    gather_k<false><<<N_NODES / 4, 256, 0, stream>>>(xwh, row, csr, dinv, b2, (void*)h2buf);

    pool_k<<<N_GRAPHS, 256, 0, stream>>>(h2buf, batch, pooled);
    mlp_k<<<N_GRAPHS, 128, 0, stream>>>(pooled, Wf1, bf1, Wf2, bf2, out);
}